// Round 8
// baseline (114.981 us; speedup 1.0000x reference)
//
#include <hip/hip_runtime.h>
#include <hip/hip_bf16.h>

// QuantumLayer: 8-qubit circuit, batch 65536.
// final = V*m; V = U(weights)*diag((-i)^popc(j)); m[b][j] = prod_q (bit? sin:cos)(x/2).
// W (fp16): [Re V; Im V] 512x256 row-major [r][k], built in-kernel (wave 0 / block).
// C = m * W^T via 16x16x32 fp16 MFMA, B held in registers (64 VGPR/wave).
// out[b][q] = sum_i sign_q(i) * (C_re[i]^2 + C_im[i]^2).
//
// One dispatch: 256 blocks x 1024 threads (16 waves -> 4 waves/SIMD, ~50% occ).
// Wave wv owns i = wv*16 + c: Re row i (f=0) and Im row 256+i (f=1) in the SAME
// lane -> p = re^2+im^2 in-lane. Grid barrier = validated r5 pattern. Per group:
// per-sg {A-frag (cvt_pkrtz), 16 MFMA, shuffle-reduce, part write}, one barrier,
// 256 threads do the 16-wave sum + store. part[] ping-pongs across groups.

typedef __attribute__((ext_vector_type(8))) _Float16 half8;
typedef __attribute__((ext_vector_type(2))) __fp16 fp16x2;   // cvt_pkrtz return type
typedef __attribute__((ext_vector_type(4))) float f32x4;

__device__ _Float16 g_W[512 * 256];
// Grid barrier state (self-cleaning; validated r5/r6).
__device__ int g_ctr = 0;
__device__ int g_sense = 0;

#define NBLK 256

__global__ __launch_bounds__(1024) void fused(const float* __restrict__ x,
                                              const float* __restrict__ wt,
                                              float* __restrict__ out) {
    __shared__ float part[2][16][32][8];   // ping-pong [wave][sample][q], 32 KB
    const int tid = threadIdx.x;
    const int bid = blockIdx.x;
    const int wv = tid >> 6;
    const int lane = tid & 63;
    const int c = lane & 15;
    const int g4 = lane >> 4;

    // ---------------- phase 1: wave 0 builds column `bid` (regs + shfl) -----
    if (wv == 0) {
        float2 a[4];   // amps i = u*64 + lane
#pragma unroll
        for (int u = 0; u < 4; ++u)
            a[u] = make_float2((u * 64 + lane) == bid ? 1.f : 0.f, 0.f);

        for (int lyr = 0; lyr < 8; ++lyr) {
#pragma unroll
            for (int q = 0; q < 8; ++q) {
                const int mask = 1 << (7 - q);
                float ty = 0.5f * wt[(lyr * 8 + q) * 2 + 0];
                float tz = 0.5f * wt[(lyr * 8 + q) * 2 + 1];
                float cy = __cosf(ty), sy = __sinf(ty);
                float ezr = __cosf(tz), ezi = __sinf(tz);
                float2 b[4];
                bool hi[4];
                if (mask == 128) {
                    b[0] = a[2]; b[1] = a[3]; b[2] = a[0]; b[3] = a[1];
                    hi[0] = false; hi[1] = false; hi[2] = true; hi[3] = true;
                } else if (mask == 64) {
                    b[0] = a[1]; b[1] = a[0]; b[2] = a[3]; b[3] = a[2];
                    hi[0] = false; hi[1] = true; hi[2] = false; hi[3] = true;
                } else {
#pragma unroll
                    for (int u = 0; u < 4; ++u) {
                        b[u].x = __shfl_xor(a[u].x, mask, 64);
                        b[u].y = __shfl_xor(a[u].y, mask, 64);
                        hi[u] = (lane & mask) != 0;
                    }
                }
#pragma unroll
                for (int u = 0; u < 4; ++u) {
                    float sgn = hi[u] ? sy : -sy;
                    float tr = cy * a[u].x + sgn * b[u].x;
                    float ti = cy * a[u].y + sgn * b[u].y;
                    float pi = hi[u] ? ezi : -ezi;
                    a[u] = make_float2(tr * ezr - ti * pi, tr * pi + ti * ezr);
                }
            }
#pragma unroll
            for (int q = 0; q < 8; ++q) {
                const int cm = 1 << (7 - q);
                const int tm = 1 << (7 - ((q + 1) & 7));
                float2 b[4];
#pragma unroll
                for (int u = 0; u < 4; ++u) {
                    if (tm == 128) b[u] = a[u ^ 2];
                    else if (tm == 64) b[u] = a[u ^ 1];
                    else {
                        b[u].x = __shfl_xor(a[u].x, tm, 64);
                        b[u].y = __shfl_xor(a[u].y, tm, 64);
                    }
                }
#pragma unroll
                for (int u = 0; u < 4; ++u) {
                    int i = u * 64 + lane;
                    a[u] = (i & cm) ? b[u] : a[u];
                }
            }
        }
        int pc = __popc(bid) & 3;
        float pr = (pc == 0) ? 1.f : (pc == 2) ? -1.f : 0.f;
        float pim = (pc == 1) ? -1.f : (pc == 3) ? 1.f : 0.f;
#pragma unroll
        for (int u = 0; u < 4; ++u) {
            int i = u * 64 + lane;
            g_W[i * 256 + bid] = (_Float16)(a[u].x * pr - a[u].y * pim);
            g_W[(i + 256) * 256 + bid] = (_Float16)(a[u].x * pim + a[u].y * pr);
        }
    }

    // ---------------- grid barrier (sense-reversing, validated r5/r6) -------
    __syncthreads();
    if (tid == 0) {
        __threadfence();
        int my_sense = __hip_atomic_load(&g_sense, __ATOMIC_RELAXED,
                                         __HIP_MEMORY_SCOPE_AGENT) ^ 1;
        int arrived = __hip_atomic_fetch_add(&g_ctr, 1, __ATOMIC_ACQ_REL,
                                             __HIP_MEMORY_SCOPE_AGENT) + 1;
        if (arrived == NBLK) {
            __hip_atomic_store(&g_ctr, 0, __ATOMIC_RELAXED,
                               __HIP_MEMORY_SCOPE_AGENT);
            __hip_atomic_store(&g_sense, my_sense, __ATOMIC_RELEASE,
                               __HIP_MEMORY_SCOPE_AGENT);
        } else {
            while (__hip_atomic_load(&g_sense, __ATOMIC_ACQUIRE,
                                     __HIP_MEMORY_SCOPE_AGENT) != my_sense) {}
        }
        __threadfence();
    }
    __syncthreads();

    // ---------------- B: wave wv owns i = wv*16+c (Re f=0, Im f=1) ----------
    // B-frag lane layout: col(row-of-W) = lane&15, k = (lane>>4)*8 + e.
    half8 bfr[2][8];
#pragma unroll
    for (int f = 0; f < 2; ++f) {
        int row = f * 256 + wv * 16 + c;
#pragma unroll
        for (int st = 0; st < 8; ++st)
            bfr[f][st] = *(const half8*)&g_W[row * 256 + st * 32 + g4 * 8];
    }

    const int iq = wv * 16 + c;   // this lane's output index i

    // ---------------- main loop: 8 groups of 32 samples ---------------------
    for (int grp = 0; grp < 8; ++grp) {
        const int sb = bid * 256 + grp * 32;

#pragma unroll
        for (int sg = 0; sg < 2; ++sg) {
            const int s = sb + sg * 16 + c;
            const float4* xp = (const float4*)(x + s * 8);
            float4 xa = xp[0], xb = xp[1];
            float cc[8], ss[8];
#pragma unroll
            for (int q = 0; q < 8; ++q) {
                float xv = 0.5f * (q < 4 ? xa[q] : xb[q - 4]);
                cc[q] = __cosf(xv);
                ss[q] = __sinf(xv);
            }
            // k bits: [7:5]=st (wires 0-2), [4:3]=g4 (wires 3-4), [2:0]=e (wires 5-7)
            float A[8], Dv[8];
#pragma unroll
            for (int t = 0; t < 8; ++t)
                A[t] = ((t & 4) ? ss[0] : cc[0]) * ((t & 2) ? ss[1] : cc[1]) * ((t & 1) ? ss[2] : cc[2]);
            const float Bf = ((g4 & 2) ? ss[3] : cc[3]) * ((g4 & 1) ? ss[4] : cc[4]);
#pragma unroll
            for (int u = 0; u < 8; ++u)
                Dv[u] = Bf * ((u & 4) ? ss[5] : cc[5]) * ((u & 2) ? ss[6] : cc[6]) * ((u & 1) ? ss[7] : cc[7]);

            f32x4 acc0 = (f32x4){0.f, 0.f, 0.f, 0.f};
            f32x4 acc1 = (f32x4){0.f, 0.f, 0.f, 0.f};
#pragma unroll
            for (int st = 0; st < 8; ++st) {
                union { half8 h8; fp16x2 h2[4]; } fr;
#pragma unroll
                for (int e2 = 0; e2 < 4; ++e2)
                    fr.h2[e2] = __builtin_amdgcn_cvt_pkrtz(A[st] * Dv[2 * e2],
                                                           A[st] * Dv[2 * e2 + 1]);
                acc0 = __builtin_amdgcn_mfma_f32_16x16x32_f16(fr.h8, bfr[0][st], acc0, 0, 0, 0);
                acc1 = __builtin_amdgcn_mfma_f32_16x16x32_f16(fr.h8, bfr[1][st], acc1, 0, 0, 0);
            }

            // ---- epilogue for this sg: p = re^2+im^2, signed 16-lane reduce ----
            // D layout: col = lane&15 -> i-offset c; row = g4*4+j -> sample in group.
#pragma unroll
            for (int j = 0; j < 4; ++j) {
                float p = acc0[j] * acc0[j] + acc1[j] * acc1[j];
                float v[8];
#pragma unroll
                for (int q = 0; q < 8; ++q)
                    v[q] = ((iq >> (7 - q)) & 1) ? -p : p;
                float t[4];
#pragma unroll
                for (int z = 0; z < 4; ++z) {
                    float keep = (c & 1) ? v[4 + z] : v[z];
                    float send = (c & 1) ? v[z] : v[4 + z];
                    t[z] = keep + __shfl_xor(send, 1, 64);
                }
                float u2[2];
#pragma unroll
                for (int z = 0; z < 2; ++z) {
                    float keep = (c & 2) ? t[2 + z] : t[z];
                    float send = (c & 2) ? t[z] : t[2 + z];
                    u2[z] = keep + __shfl_xor(send, 2, 64);
                }
                float keep = (c & 4) ? u2[1] : u2[0];
                float send = (c & 4) ? u2[0] : u2[1];
                float w1 = keep + __shfl_xor(send, 4, 64);
                w1 += __shfl_xor(w1, 8, 64);
                if (c < 8) {
                    int qq = (c & 1) * 4 + ((c >> 1) & 1) * 2 + ((c >> 2) & 1);
                    part[grp & 1][wv][sg * 16 + g4 * 4 + j][qq] = w1;
                }
            }
        }
        __syncthreads();
        if (tid < 256) {
            int s = tid >> 3, q = tid & 7;
            float sum = 0.f;
#pragma unroll
            for (int w = 0; w < 16; ++w) sum += part[grp & 1][w][s][q];
            out[(sb + s) * 8 + q] = sum;
        }
        // no second barrier: next group writes the other part[] buffer; reuse of
        // this buffer (grp+2) happens only after barrier grp+1, by which time
        // all readers above have finished.
    }
}

extern "C" void kernel_launch(void* const* d_in, const int* in_sizes, int n_in,
                              void* d_out, int out_size, void* d_ws, size_t ws_size,
                              hipStream_t stream) {
    const float* x = (const float*)d_in[0];       // (65536, 8) f32
    const float* wt = (const float*)d_in[1];      // (8, 8, 2) f32
    float* out = (float*)d_out;                   // (65536, 8) f32
    (void)d_ws; (void)ws_size; (void)in_sizes; (void)n_in; (void)out_size;

    fused<<<NBLK, 1024, 0, stream>>>(x, wt, out);
}

// Round 9
// 93.198 us; speedup vs baseline: 1.2337x; 1.2337x over previous
//
#include <hip/hip_runtime.h>
#include <hip/hip_bf16.h>

// QuantumLayer: 8-qubit circuit, batch 65536.
// final = V*m; V = U(weights)*diag((-i)^popc(j)); m[b][j] = prod_q (bit? sin:cos)(x/2).
// W (fp16): [Re V; Im V] 512x256 [r][k], built in-kernel; B-operand in registers.
// C = m * W^T via 16x16x32 fp16 MFMA; out[b][q] = sum_i sign_q(i)*(Cre^2+Cim^2)
// computed by a SECOND MFMA: D2[q][s] = S_frag (+-1, K<=16) x P^T.
//
// r9 restructure vs r8 (103us, VALU-duplication-bound):
//  * A-fragments built ONCE per group in LDS (trig 256 thr, products 1024 thr,
//    XOR-swizzled image) -> 16x less A-side VALU; waves ds_read_b128 fragments.
//  * epilogue shuffle-tree (64 ds_swizzle/wave/grp) -> per-wave LDS transpose
//    (1 w128 + 8 r32) + 1 sign-MFMA; cross-wave sum via padded part[] reduce.
// One dispatch, 256 blocks x 1024 thr; phase1 + grid barrier validated r5-r8.

typedef _Float16 half8 __attribute__((ext_vector_type(8)));
typedef __fp16 fp16x2 __attribute__((ext_vector_type(2)));
typedef float f32x4 __attribute__((ext_vector_type(4)));

__device__ _Float16 g_W[512 * 256];
// Grid barrier state (self-cleaning; validated r5/r6/r8).
__device__ int g_ctr = 0;
__device__ int g_sense = 0;

#define NBLK 256
// LDS map (bytes)
#define TRIG_OFF 0          // float[32][16]: [s][0..7]=cos, [8..15]=sin   (2 KB)
#define AIMG_OFF 2048       // fp16[32][256] A-image, XOR-swizzled        (16 KB)
#define PT_OFF   18432      // per-wave f32[16][20] transpose scratch     (20 KB)
#define PART_OFF 38912      // float[2][16 wv][33 rows pad][8 q]          (33 KB)

__global__ __launch_bounds__(1024) void fused(const float* __restrict__ x,
                                              const float* __restrict__ wt,
                                              float* __restrict__ out) {
    __shared__ __align__(16) char smem[72704];
    const int tid = threadIdx.x;
    const int bid = blockIdx.x;
    const int wv = tid >> 6;
    const int lane = tid & 63;
    const int c = lane & 15;
    const int g4 = lane >> 4;

    // ---------------- phase 1: wave 0 builds column `bid` (regs + shfl) -----
    if (wv == 0) {
        float2 a[4];   // amps i = u*64 + lane
#pragma unroll
        for (int u = 0; u < 4; ++u)
            a[u] = make_float2((u * 64 + lane) == bid ? 1.f : 0.f, 0.f);

        for (int lyr = 0; lyr < 8; ++lyr) {
#pragma unroll
            for (int q = 0; q < 8; ++q) {
                const int mask = 1 << (7 - q);
                float ty = 0.5f * wt[(lyr * 8 + q) * 2 + 0];
                float tz = 0.5f * wt[(lyr * 8 + q) * 2 + 1];
                float cy = __cosf(ty), sy = __sinf(ty);
                float ezr = __cosf(tz), ezi = __sinf(tz);
                float2 b[4];
                bool hi[4];
                if (mask == 128) {
                    b[0] = a[2]; b[1] = a[3]; b[2] = a[0]; b[3] = a[1];
                    hi[0] = false; hi[1] = false; hi[2] = true; hi[3] = true;
                } else if (mask == 64) {
                    b[0] = a[1]; b[1] = a[0]; b[2] = a[3]; b[3] = a[2];
                    hi[0] = false; hi[1] = true; hi[2] = false; hi[3] = true;
                } else {
#pragma unroll
                    for (int u = 0; u < 4; ++u) {
                        b[u].x = __shfl_xor(a[u].x, mask, 64);
                        b[u].y = __shfl_xor(a[u].y, mask, 64);
                        hi[u] = (lane & mask) != 0;
                    }
                }
#pragma unroll
                for (int u = 0; u < 4; ++u) {
                    float sgn = hi[u] ? sy : -sy;
                    float tr = cy * a[u].x + sgn * b[u].x;
                    float ti = cy * a[u].y + sgn * b[u].y;
                    float pi = hi[u] ? ezi : -ezi;
                    a[u] = make_float2(tr * ezr - ti * pi, tr * pi + ti * ezr);
                }
            }
#pragma unroll
            for (int q = 0; q < 8; ++q) {
                const int cm = 1 << (7 - q);
                const int tm = 1 << (7 - ((q + 1) & 7));
                float2 b[4];
#pragma unroll
                for (int u = 0; u < 4; ++u) {
                    if (tm == 128) b[u] = a[u ^ 2];
                    else if (tm == 64) b[u] = a[u ^ 1];
                    else {
                        b[u].x = __shfl_xor(a[u].x, tm, 64);
                        b[u].y = __shfl_xor(a[u].y, tm, 64);
                    }
                }
#pragma unroll
                for (int u = 0; u < 4; ++u) {
                    int i = u * 64 + lane;
                    a[u] = (i & cm) ? b[u] : a[u];
                }
            }
        }
        int pc = __popc(bid) & 3;
        float pr = (pc == 0) ? 1.f : (pc == 2) ? -1.f : 0.f;
        float pim = (pc == 1) ? -1.f : (pc == 3) ? 1.f : 0.f;
#pragma unroll
        for (int u = 0; u < 4; ++u) {
            int i = u * 64 + lane;
            g_W[i * 256 + bid] = (_Float16)(a[u].x * pr - a[u].y * pim);
            g_W[(i + 256) * 256 + bid] = (_Float16)(a[u].x * pim + a[u].y * pr);
        }
    }

    // ---------------- grid barrier (sense-reversing, validated r5-r8) -------
    __syncthreads();
    if (tid == 0) {
        __threadfence();
        int my_sense = __hip_atomic_load(&g_sense, __ATOMIC_RELAXED,
                                         __HIP_MEMORY_SCOPE_AGENT) ^ 1;
        int arrived = __hip_atomic_fetch_add(&g_ctr, 1, __ATOMIC_ACQ_REL,
                                             __HIP_MEMORY_SCOPE_AGENT) + 1;
        if (arrived == NBLK) {
            __hip_atomic_store(&g_ctr, 0, __ATOMIC_RELAXED,
                               __HIP_MEMORY_SCOPE_AGENT);
            __hip_atomic_store(&g_sense, my_sense, __ATOMIC_RELEASE,
                               __HIP_MEMORY_SCOPE_AGENT);
        } else {
            while (__hip_atomic_load(&g_sense, __ATOMIC_ACQUIRE,
                                     __HIP_MEMORY_SCOPE_AGENT) != my_sense) {}
        }
        __threadfence();
    }
    __syncthreads();

    // ---------------- B: wave wv owns i = wv*16+c (Re f=0, Im f=1) ----------
    half8 bfr[2][8];
#pragma unroll
    for (int f = 0; f < 2; ++f) {
        int row = f * 256 + wv * 16 + c;
#pragma unroll
        for (int st = 0; st < 8; ++st)
            bfr[f][st] = *(const half8*)&g_W[row * 256 + st * 32 + g4 * 8];
    }

    // sign A-fragment for epilogue MFMA: row(m)=c -> q, k = g4*8+e = i_local,
    // zero for k>=16 (g4>=2). Rows c>=8 of D2 never read (c&7 guards UB shift).
    half8 sfrag;
#pragma unroll
    for (int e = 0; e < 8; ++e) {
        int il = g4 * 8 + e;
        float sv = (g4 < 2)
            ? ((((wv * 16 + il) >> (7 - (c & 7))) & 1) ? -1.f : 1.f) : 0.f;
        sfrag[e] = (_Float16)sv;
    }

    // ---------------- main loop: 8 groups of 32 samples ---------------------
    for (int grp = 0; grp < 8; ++grp) {
        const int sb = bid * 256 + grp * 32;
        const int pp = grp & 1;

        // ---- stage A: trig, once per group (coalesced x load) ----
        if (tid < 256) {
            float xv = 0.5f * x[sb * 8 + tid];
            float* trow = (float*)(smem + TRIG_OFF + (tid >> 3) * 64);
            int q = tid & 7;
            trow[q] = __cosf(xv);
            trow[8 + q] = __sinf(xv);
        }
        __syncthreads();

        // ---- stage B: A-image, 1024 work items = 32 samples x 32 k-octets ----
        {
            int sl = tid >> 5, oct = tid & 31;
            const f32x4* tg = (const f32x4*)(smem + TRIG_OFF + sl * 64);
            f32x4 c03 = tg[0], c47 = tg[1], s03 = tg[2], s47 = tg[3];
            // wire w <-> bit (7-w) of k; oct = k[7:3] (wires 0..4), e = k[2:0]
            float f0 = (oct & 16) ? s03[0] : c03[0];
            float f1 = (oct & 8) ? s03[1] : c03[1];
            float f2 = (oct & 4) ? s03[2] : c03[2];
            float f3 = (oct & 2) ? s03[3] : c03[3];
            float f4 = (oct & 1) ? s47[0] : c47[0];
            float P5 = f0 * f1 * f2 * f3 * f4;
            float c5 = c47[1], s5 = s47[1];
            float c6 = c47[2], s6 = s47[2];
            float c7 = c47[3], s7 = s47[3];
            float u0 = P5 * (c5 * c6), u1 = P5 * (c5 * s6);
            float u2 = P5 * (s5 * c6), u3 = P5 * (s5 * s6);
            union { half8 h8; fp16x2 h2[4]; } w;
            w.h2[0] = __builtin_amdgcn_cvt_pkrtz(u0 * c7, u0 * s7);
            w.h2[1] = __builtin_amdgcn_cvt_pkrtz(u1 * c7, u1 * s7);
            w.h2[2] = __builtin_amdgcn_cvt_pkrtz(u2 * c7, u2 * s7);
            w.h2[3] = __builtin_amdgcn_cvt_pkrtz(u3 * c7, u3 * s7);
            int byte = AIMG_OFF + sl * 512 + ((oct * 16) ^ ((sl & 7) << 4));
            *(half8*)(smem + byte) = w.h8;
        }
        __syncthreads();

        // ---- GEMM + MFMA epilogue, per 16-sample half ----
#pragma unroll
        for (int sg = 0; sg < 2; ++sg) {
            const int sl = sg * 16 + c;
            const int rowbase = AIMG_OFF + sl * 512;
            const int swz = (sl & 7) << 4;
            f32x4 acc0 = (f32x4){0.f, 0.f, 0.f, 0.f};
            f32x4 acc1 = (f32x4){0.f, 0.f, 0.f, 0.f};
#pragma unroll
            for (int st = 0; st < 8; ++st) {
                half8 afr = *(const half8*)(smem + rowbase + ((st * 64 + g4 * 16) ^ swz));
                acc0 = __builtin_amdgcn_mfma_f32_16x16x32_f16(afr, bfr[0][st], acc0, 0, 0, 0);
                acc1 = __builtin_amdgcn_mfma_f32_16x16x32_f16(afr, bfr[1][st], acc1, 0, 0, 0);
            }

            // p = re^2+im^2; per-wave LDS transpose (wave-synchronous, no barrier)
            f32x4 pv;
#pragma unroll
            for (int j = 0; j < 4; ++j)
                pv[j] = acc0[j] * acc0[j] + acc1[j] * acc1[j];
            char* ptb = smem + PT_OFF + wv * 1280;   // f32[16 rows][pitch 80B]
            *(f32x4*)(ptb + c * 80 + g4 * 16) = pv;  // row=i_local=c, col=s16=g4*4+j

            union { half8 h8; fp16x2 h2[4]; } bu;
            if (g4 < 2) {
                float pe[8];
#pragma unroll
                for (int e = 0; e < 8; ++e)
                    pe[e] = *(const float*)(ptb + (g4 * 8 + e) * 80 + c * 4);
                bu.h2[0] = __builtin_amdgcn_cvt_pkrtz(pe[0], pe[1]);
                bu.h2[1] = __builtin_amdgcn_cvt_pkrtz(pe[2], pe[3]);
                bu.h2[2] = __builtin_amdgcn_cvt_pkrtz(pe[4], pe[5]);
                bu.h2[3] = __builtin_amdgcn_cvt_pkrtz(pe[6], pe[7]);
            } else {
                bu.h8 = (half8){0, 0, 0, 0, 0, 0, 0, 0};
            }
            // D2[q][s16] = sum_{i_local<16} sign_q(wv*16+i_local) * p[i_local][s16]
            f32x4 d2 = __builtin_amdgcn_mfma_f32_16x16x32_f16(
                sfrag, bu.h8, (f32x4){0.f, 0.f, 0.f, 0.f}, 0, 0, 0);
            if (g4 < 2)
                *(f32x4*)(smem + PART_OFF + pp * 16896 + wv * 1056 + sl * 32 + g4 * 16) = d2;
        }
        __syncthreads();

        // ---- cross-wave sum + store ----
        if (tid < 256) {
            int s2 = tid >> 3, q = tid & 7;
            const char* pb = smem + PART_OFF + pp * 16896 + s2 * 32 + q * 4;
            float sum = 0.f;
#pragma unroll
            for (int w = 0; w < 16; ++w)
                sum += *(const float*)(pb + w * 1056);
            out[(sb + s2) * 8 + q] = sum;
        }
        // no extra barrier: part[] ping-pongs; trig/aimg rewrites are fenced by
        // the two barriers at the top of the next group's stages.
    }
}

extern "C" void kernel_launch(void* const* d_in, const int* in_sizes, int n_in,
                              void* d_out, int out_size, void* d_ws, size_t ws_size,
                              hipStream_t stream) {
    const float* x = (const float*)d_in[0];       // (65536, 8) f32
    const float* wt = (const float*)d_in[1];      // (8, 8, 2) f32
    float* out = (float*)d_out;                   // (65536, 8) f32
    (void)d_ws; (void)ws_size; (void)in_sizes; (void)n_in; (void)out_size;

    fused<<<NBLK, 1024, 0, stream>>>(x, wt, out);
}

// Round 10
// 90.188 us; speedup vs baseline: 1.2749x; 1.0334x over previous
//
#include <hip/hip_runtime.h>
#include <hip/hip_bf16.h>

// QuantumLayer: 8-qubit circuit, batch 65536.
// final = V*m; V = U(weights)*diag((-i)^popc(j)); m[b][j] = prod_q (bit? sin:cos)(x/2).
// W (fp16): [Re V; Im V] 512x256 [r][k], built in-kernel; B-operand in registers.
// C = m * W^T via 16x16x32 fp16 MFMA; out[b][q] = sum_i sign_q(i)*(Cre^2+Cim^2)
// via per-wave fp16-LDS transpose + one sign-MFMA; cross-wave sum in LDS.
//
// r10 vs r9 (78us, lockstep-latency-bound, all pipes <10%):
//  * trig for ALL 256 block-samples built once, BEFORE the grid barrier.
//  * A-image and PART double-buffered -> ONE barrier per 32-sample group;
//    stageB(g+1) issues inside the same section as GEMM(g) (latency overlap);
//    sum(g) overlaps section g+1. Barriers/block: 26 -> 11.
//  * PT transpose scratch in fp16 (b64 write, 8xu16 read, no re-cvt).

typedef _Float16 half8 __attribute__((ext_vector_type(8)));
typedef __fp16 fp16x2 __attribute__((ext_vector_type(2)));
typedef float f32x4 __attribute__((ext_vector_type(4)));

__device__ _Float16 g_W[512 * 256];
// Grid barrier state (self-cleaning; validated r5-r9).
__device__ int g_ctr = 0;
__device__ int g_sense = 0;

#define NBLK 256
// LDS map (bytes)
#define TRIG_OFF 0       // float[256][16]: cos0-7, sin0-7 per sample   (16 KB)
#define A0_OFF   16384   // fp16[32][256] A-image buf0, XOR-swizzled    (16 KB)
#define A1_OFF   32768   // buf1                                        (16 KB)
#define PT_OFF   49152   // per-wave fp16[16 rows][pitch 40B] = 640B    (10 KB)
#define P0_OFF   59392   // PART buf0: 16 waves x 1056B                 (16.5 KB)
#define P1_OFF   76288   // PART buf1                                   (16.5 KB)
// total 93184

__global__ __launch_bounds__(1024) void fused(const float* __restrict__ x,
                                              const float* __restrict__ wt,
                                              float* __restrict__ out) {
    __shared__ __align__(16) char smem[93184];
    const int tid = threadIdx.x;
    const int bid = blockIdx.x;
    const int wv = tid >> 6;
    const int lane = tid & 63;
    const int c = lane & 15;
    const int g4 = lane >> 4;

    // ---- trig for this block's 256 samples (all 16 waves; before phase 1,
    //      so its latency hides under phase-1 / grid-barrier skew) ----
#pragma unroll
    for (int it = 0; it < 2; ++it) {
        int item = tid + it * 1024;                 // 0..2047 = sample*8 + q
        float xv = 0.5f * x[bid * 2048 + item];
        float* trow = (float*)(smem + TRIG_OFF + (item >> 3) * 64);
        int q = item & 7;
        trow[q] = __cosf(xv);
        trow[8 + q] = __sinf(xv);
    }

    // ---------------- phase 1: wave 0 builds column `bid` (regs + shfl) -----
    if (wv == 0) {
        float2 a[4];   // amps i = u*64 + lane
#pragma unroll
        for (int u = 0; u < 4; ++u)
            a[u] = make_float2((u * 64 + lane) == bid ? 1.f : 0.f, 0.f);

        for (int lyr = 0; lyr < 8; ++lyr) {
#pragma unroll
            for (int q = 0; q < 8; ++q) {
                const int mask = 1 << (7 - q);
                float ty = 0.5f * wt[(lyr * 8 + q) * 2 + 0];
                float tz = 0.5f * wt[(lyr * 8 + q) * 2 + 1];
                float cy = __cosf(ty), sy = __sinf(ty);
                float ezr = __cosf(tz), ezi = __sinf(tz);
                float2 b[4];
                bool hi[4];
                if (mask == 128) {
                    b[0] = a[2]; b[1] = a[3]; b[2] = a[0]; b[3] = a[1];
                    hi[0] = false; hi[1] = false; hi[2] = true; hi[3] = true;
                } else if (mask == 64) {
                    b[0] = a[1]; b[1] = a[0]; b[2] = a[3]; b[3] = a[2];
                    hi[0] = false; hi[1] = true; hi[2] = false; hi[3] = true;
                } else {
#pragma unroll
                    for (int u = 0; u < 4; ++u) {
                        b[u].x = __shfl_xor(a[u].x, mask, 64);
                        b[u].y = __shfl_xor(a[u].y, mask, 64);
                        hi[u] = (lane & mask) != 0;
                    }
                }
#pragma unroll
                for (int u = 0; u < 4; ++u) {
                    float sgn = hi[u] ? sy : -sy;
                    float tr = cy * a[u].x + sgn * b[u].x;
                    float ti = cy * a[u].y + sgn * b[u].y;
                    float pi = hi[u] ? ezi : -ezi;
                    a[u] = make_float2(tr * ezr - ti * pi, tr * pi + ti * ezr);
                }
            }
#pragma unroll
            for (int q = 0; q < 8; ++q) {
                const int cm = 1 << (7 - q);
                const int tm = 1 << (7 - ((q + 1) & 7));
                float2 b[4];
#pragma unroll
                for (int u = 0; u < 4; ++u) {
                    if (tm == 128) b[u] = a[u ^ 2];
                    else if (tm == 64) b[u] = a[u ^ 1];
                    else {
                        b[u].x = __shfl_xor(a[u].x, tm, 64);
                        b[u].y = __shfl_xor(a[u].y, tm, 64);
                    }
                }
#pragma unroll
                for (int u = 0; u < 4; ++u) {
                    int i = u * 64 + lane;
                    a[u] = (i & cm) ? b[u] : a[u];
                }
            }
        }
        int pc = __popc(bid) & 3;
        float pr = (pc == 0) ? 1.f : (pc == 2) ? -1.f : 0.f;
        float pim = (pc == 1) ? -1.f : (pc == 3) ? 1.f : 0.f;
#pragma unroll
        for (int u = 0; u < 4; ++u) {
            int i = u * 64 + lane;
            g_W[i * 256 + bid] = (_Float16)(a[u].x * pr - a[u].y * pim);
            g_W[(i + 256) * 256 + bid] = (_Float16)(a[u].x * pim + a[u].y * pr);
        }
    }

    // ---------------- grid barrier (sense-reversing, validated r5-r9) -------
    __syncthreads();
    if (tid == 0) {
        __threadfence();
        int my_sense = __hip_atomic_load(&g_sense, __ATOMIC_RELAXED,
                                         __HIP_MEMORY_SCOPE_AGENT) ^ 1;
        int arrived = __hip_atomic_fetch_add(&g_ctr, 1, __ATOMIC_ACQ_REL,
                                             __HIP_MEMORY_SCOPE_AGENT) + 1;
        if (arrived == NBLK) {
            __hip_atomic_store(&g_ctr, 0, __ATOMIC_RELAXED,
                               __HIP_MEMORY_SCOPE_AGENT);
            __hip_atomic_store(&g_sense, my_sense, __ATOMIC_RELEASE,
                               __HIP_MEMORY_SCOPE_AGENT);
        } else {
            while (__hip_atomic_load(&g_sense, __ATOMIC_ACQUIRE,
                                     __HIP_MEMORY_SCOPE_AGENT) != my_sense) {
                __builtin_amdgcn_s_sleep(2);
            }
        }
        __threadfence();
    }
    __syncthreads();

    // ---------------- B: wave wv owns i = wv*16+c (Re f=0, Im f=1) ----------
    half8 bfr[2][8];
#pragma unroll
    for (int f = 0; f < 2; ++f) {
        int row = f * 256 + wv * 16 + c;
#pragma unroll
        for (int st = 0; st < 8; ++st)
            bfr[f][st] = *(const half8*)&g_W[row * 256 + st * 32 + g4 * 8];
    }

    // sign A-fragment for epilogue MFMA: row(m)=c -> q, k = g4*8+e = i_local,
    // zero for k>=16 (g4>=2). Rows c>=8 of D2 never read.
    half8 sfrag;
#pragma unroll
    for (int e = 0; e < 8; ++e) {
        int il = g4 * 8 + e;
        float sv = (g4 < 2)
            ? ((((wv * 16 + il) >> (7 - (c & 7))) & 1) ? -1.f : 1.f) : 0.f;
        sfrag[e] = (_Float16)sv;
    }

    char* const ptb = smem + PT_OFF + wv * 640;   // fp16[16][pitch 40B]

    // ---- stageB(0): A-image for samples 0..31 into A0 ----
    {
        int sl = tid >> 5, oct = tid & 31;
        const f32x4* tg = (const f32x4*)(smem + TRIG_OFF + sl * 64);
        f32x4 c03 = tg[0], c47 = tg[1], s03 = tg[2], s47 = tg[3];
        float f0 = (oct & 16) ? s03[0] : c03[0];
        float f1 = (oct & 8) ? s03[1] : c03[1];
        float f2 = (oct & 4) ? s03[2] : c03[2];
        float f3 = (oct & 2) ? s03[3] : c03[3];
        float f4 = (oct & 1) ? s47[0] : c47[0];
        float P5 = f0 * f1 * f2 * f3 * f4;
        float c5 = c47[1], s5 = s47[1], c6 = c47[2], s6 = s47[2];
        float c7 = c47[3], s7 = s47[3];
        float u0 = P5 * (c5 * c6), u1 = P5 * (c5 * s6);
        float u2 = P5 * (s5 * c6), u3 = P5 * (s5 * s6);
        union { half8 h8; fp16x2 h2[4]; } w;
        w.h2[0] = __builtin_amdgcn_cvt_pkrtz(u0 * c7, u0 * s7);
        w.h2[1] = __builtin_amdgcn_cvt_pkrtz(u1 * c7, u1 * s7);
        w.h2[2] = __builtin_amdgcn_cvt_pkrtz(u2 * c7, u2 * s7);
        w.h2[3] = __builtin_amdgcn_cvt_pkrtz(u3 * c7, u3 * s7);
        *(half8*)(smem + A0_OFF + sl * 512 + ((oct * 16) ^ ((sl & 7) << 4))) = w.h8;
    }
    __syncthreads();

    // ---------------- main loop: 8 groups x 32 samples, 1 barrier/group -----
    for (int g = 0; g < 8; ++g) {
        const int abase = (g & 1) ? A1_OFF : A0_OFF;
        const int pbase = (g & 1) ? P1_OFF : P0_OFF;

        // ---- stageB(g+1) into the other A buffer (overlaps GEMM below) ----
        if (g < 7) {
            const int nbase = (g & 1) ? A0_OFF : A1_OFF;
            int sl = tid >> 5, oct = tid & 31;
            const f32x4* tg = (const f32x4*)(smem + TRIG_OFF + ((g + 1) * 32 + sl) * 64);
            f32x4 c03 = tg[0], c47 = tg[1], s03 = tg[2], s47 = tg[3];
            float f0 = (oct & 16) ? s03[0] : c03[0];
            float f1 = (oct & 8) ? s03[1] : c03[1];
            float f2 = (oct & 4) ? s03[2] : c03[2];
            float f3 = (oct & 2) ? s03[3] : c03[3];
            float f4 = (oct & 1) ? s47[0] : c47[0];
            float P5 = f0 * f1 * f2 * f3 * f4;
            float c5 = c47[1], s5 = s47[1], c6 = c47[2], s6 = s47[2];
            float c7 = c47[3], s7 = s47[3];
            float u0 = P5 * (c5 * c6), u1 = P5 * (c5 * s6);
            float u2 = P5 * (s5 * c6), u3 = P5 * (s5 * s6);
            union { half8 h8; fp16x2 h2[4]; } w;
            w.h2[0] = __builtin_amdgcn_cvt_pkrtz(u0 * c7, u0 * s7);
            w.h2[1] = __builtin_amdgcn_cvt_pkrtz(u1 * c7, u1 * s7);
            w.h2[2] = __builtin_amdgcn_cvt_pkrtz(u2 * c7, u2 * s7);
            w.h2[3] = __builtin_amdgcn_cvt_pkrtz(u3 * c7, u3 * s7);
            *(half8*)(smem + nbase + sl * 512 + ((oct * 16) ^ ((sl & 7) << 4))) = w.h8;
        }

        // ---- GEMM + epilogue for group g ----
#pragma unroll
        for (int sg = 0; sg < 2; ++sg) {
            const int sl = sg * 16 + c;
            const int rowbase = abase + sl * 512;
            const int swz = (sl & 7) << 4;
            f32x4 acc0 = (f32x4){0.f, 0.f, 0.f, 0.f};
            f32x4 acc1 = (f32x4){0.f, 0.f, 0.f, 0.f};
#pragma unroll
            for (int st = 0; st < 8; ++st) {
                half8 afr = *(const half8*)(smem + rowbase + ((st * 64 + g4 * 16) ^ swz));
                acc0 = __builtin_amdgcn_mfma_f32_16x16x32_f16(afr, bfr[0][st], acc0, 0, 0, 0);
                acc1 = __builtin_amdgcn_mfma_f32_16x16x32_f16(afr, bfr[1][st], acc1, 0, 0, 0);
            }

            // p = re^2+im^2 -> fp16 PT (per-wave, wave-synchronous transpose)
            fp16x2 pk01 = __builtin_amdgcn_cvt_pkrtz(
                acc0[0] * acc0[0] + acc1[0] * acc1[0],
                acc0[1] * acc0[1] + acc1[1] * acc1[1]);
            fp16x2 pk23 = __builtin_amdgcn_cvt_pkrtz(
                acc0[2] * acc0[2] + acc1[2] * acc1[2],
                acc0[3] * acc0[3] + acc1[3] * acc1[3]);
            char* pw = ptb + c * 40 + g4 * 8;   // row = i_local = c, col = g4*4+j
            *(fp16x2*)pw = pk01;
            *(fp16x2*)(pw + 4) = pk23;

            half8 bu;
            if (g4 < 2) {
#pragma unroll
                for (int e = 0; e < 8; ++e)
                    bu[e] = *(const _Float16*)(ptb + (g4 * 8 + e) * 40 + c * 2);
            } else {
                bu = (half8){0, 0, 0, 0, 0, 0, 0, 0};
            }
            // D2[q][s16] = sum_{il<16} sign_q(wv*16+il) * p[il][s16]
            f32x4 d2 = __builtin_amdgcn_mfma_f32_16x16x32_f16(
                sfrag, bu, (f32x4){0.f, 0.f, 0.f, 0.f}, 0, 0, 0);
            if (g4 < 2)
                *(f32x4*)(smem + pbase + wv * 1056 + sl * 32 + g4 * 16) = d2;
        }
        __syncthreads();   // PART[g&1] ready AND A[(g+1)&1] ready

        // ---- cross-wave sum + store (overlaps next section) ----
        if (tid < 256) {
            int s2 = tid >> 3, q = tid & 7;
            const char* pb = smem + pbase + s2 * 32 + q * 4;
            float sum = 0.f;
#pragma unroll
            for (int w = 0; w < 16; ++w)
                sum += *(const float*)(pb + w * 1056);
            out[(bid * 256 + g * 32 + s2) * 8 + q] = sum;
        }
        // no barrier: next section writes A[g&1] (GEMM(g) reads done pre-barrier)
        // and PART[(g+1)&1] (disjoint from PART[g&1] being read here).
    }
}

extern "C" void kernel_launch(void* const* d_in, const int* in_sizes, int n_in,
                              void* d_out, int out_size, void* d_ws, size_t ws_size,
                              hipStream_t stream) {
    const float* x = (const float*)d_in[0];       // (65536, 8) f32
    const float* wt = (const float*)d_in[1];      // (8, 8, 2) f32
    float* out = (float*)d_out;                   // (65536, 8) f32
    (void)d_ws; (void)ws_size; (void)in_sizes; (void)n_in; (void)out_size;

    fused<<<NBLK, 1024, 0, stream>>>(x, wt, out);
}

// Round 11
// 77.778 us; speedup vs baseline: 1.4783x; 1.1596x over previous
//
#include <hip/hip_runtime.h>
#include <hip/hip_bf16.h>

// QuantumLayer: 8-qubit circuit, batch 65536.
// final = V*m; V = U(weights)*diag((-i)^popc(j)); m[b][j] = prod_q (bit? sin:cos)(x/2).
// W (fp16): [Re V; Im V] 512x256 [r][k], built in-kernel; B-operand in registers.
// Swapped GEMM: C^T = W_rows x m via mfma(bfr, afr) -> lane holds p[i][s] directly;
// sign-MFMA B-frag assembled with 4 ds_bpermute (no LDS transpose).
// out[b][q] = sum_i sign_q(i) * (C_re[i]^2 + C_im[i]^2).
//
// r11 vs r10 (75us, latency-bound, all pipes ~10%):
//  * epilogue LDS round-trip (PT) eliminated via operand-swapped MFMA + bpermute.
//  * phase-1: gate params precomputed to LDS (no in-chain global loads);
//    8 CNOTs/layer fused into ONE precomputed GF(2) permutation (depth 1).
//  * grid-barrier spin polls RELAXED + one acquire at exit.

typedef _Float16 half8 __attribute__((ext_vector_type(8)));
typedef __fp16 fp16x2 __attribute__((ext_vector_type(2)));
typedef float f32x4 __attribute__((ext_vector_type(4)));

__device__ _Float16 g_W[512 * 256];
// Grid barrier state (self-cleaning; validated r5-r10).
__device__ int g_ctr = 0;
__device__ int g_sense = 0;

#define NBLK 256
// LDS map (bytes)
#define TRIG_OFF 0       // float[256][16]: cos0-7, sin0-7 per sample   (16 KB)
#define A0_OFF   16384   // fp16[32][256] A-image buf0, XOR-swizzled    (16 KB)
#define A1_OFF   32768   // buf1                                        (16 KB)
#define P0_OFF   49152   // PART buf0: 16 waves x 1056B                 (16.5 KB)
#define P1_OFF   66048   // PART buf1                                   (16.5 KB)
#define PRM_OFF  16384   // phase-1 gate params float4[64] - overlaps A0 (pre-barrier only)
// total 82944

static __device__ __forceinline__ int f_as_i(float f) { union { float f; int i; } u; u.f = f; return u.i; }
static __device__ __forceinline__ float i_as_f(int i) { union { float f; int i; } u; u.i = i; return u.f; }

static __device__ __forceinline__ void stage_a(char* smem, int samp_row, int abase, int tid) {
    int sl = tid >> 5, oct = tid & 31;
    const f32x4* tg = (const f32x4*)(smem + TRIG_OFF + (samp_row + sl) * 64);
    f32x4 c03 = tg[0], c47 = tg[1], s03 = tg[2], s47 = tg[3];
    // wire w <-> bit (7-w) of k; oct = k[7:3] (wires 0..4), e = k[2:0]
    float f0 = (oct & 16) ? s03[0] : c03[0];
    float f1 = (oct & 8) ? s03[1] : c03[1];
    float f2 = (oct & 4) ? s03[2] : c03[2];
    float f3 = (oct & 2) ? s03[3] : c03[3];
    float f4 = (oct & 1) ? s47[0] : c47[0];
    float P5 = f0 * f1 * f2 * f3 * f4;
    float c5 = c47[1], s5 = s47[1], c6 = c47[2], s6 = s47[2];
    float c7 = c47[3], s7 = s47[3];
    float u0 = P5 * (c5 * c6), u1 = P5 * (c5 * s6);
    float u2 = P5 * (s5 * c6), u3 = P5 * (s5 * s6);
    union { half8 h8; fp16x2 h2[4]; } w;
    w.h2[0] = __builtin_amdgcn_cvt_pkrtz(u0 * c7, u0 * s7);
    w.h2[1] = __builtin_amdgcn_cvt_pkrtz(u1 * c7, u1 * s7);
    w.h2[2] = __builtin_amdgcn_cvt_pkrtz(u2 * c7, u2 * s7);
    w.h2[3] = __builtin_amdgcn_cvt_pkrtz(u3 * c7, u3 * s7);
    *(half8*)(smem + abase + sl * 512 + ((oct * 16) ^ ((sl & 7) << 4))) = w.h8;
}

__global__ __launch_bounds__(1024) void fused(const float* __restrict__ x,
                                              const float* __restrict__ wt,
                                              float* __restrict__ out) {
    __shared__ __align__(16) char smem[82944];
    const int tid = threadIdx.x;
    const int bid = blockIdx.x;
    const int wv = tid >> 6;
    const int lane = tid & 63;
    const int c = lane & 15;
    const int g4 = lane >> 4;

    // ---- trig for this block's 256 samples (all waves, pre-grid-barrier) ----
#pragma unroll
    for (int it = 0; it < 2; ++it) {
        int item = tid + it * 1024;                 // sample*8 + q
        float xv = 0.5f * x[bid * 2048 + item];
        float* trow = (float*)(smem + TRIG_OFF + (item >> 3) * 64);
        int q = item & 7;
        trow[q] = __cosf(xv);
        trow[8 + q] = __sinf(xv);
    }

    // ---------------- phase 1: wave 0 builds column `bid` -------------------
    if (wv == 0) {
        // gate params precomputed lane-parallel: lane g -> gate g (lyr*8+q)
        {
            float2 w2 = *(const float2*)(wt + 2 * lane);
            float4 pr;
            pr.x = __cosf(0.5f * w2.x);
            pr.y = __sinf(0.5f * w2.x);
            pr.z = __cosf(0.5f * w2.y);
            pr.w = __sinf(0.5f * w2.y);
            *(float4*)(smem + PRM_OFF + lane * 16) = pr;
        }
        // fused CNOT-layer permutation: j = src_0(src_1(...src_7(i)))
        int jm[4];
#pragma unroll
        for (int u = 0; u < 4; ++u) {
            int j = u * 64 + lane;
#pragma unroll
            for (int q = 7; q >= 0; --q) {
                int cm = 1 << (7 - q);
                int tm = 1 << (7 - ((q + 1) & 7));
                j = (j & cm) ? (j ^ tm) : j;
            }
            jm[u] = j;
        }

        float2 a[4];   // amps i = u*64 + lane
#pragma unroll
        for (int u = 0; u < 4; ++u)
            a[u] = make_float2((u * 64 + lane) == bid ? 1.f : 0.f, 0.f);

        for (int lyr = 0; lyr < 8; ++lyr) {
#pragma unroll
            for (int q = 0; q < 8; ++q) {
                float4 pr4 = *(const float4*)(smem + PRM_OFF + (lyr * 8 + q) * 16);
                float cy = pr4.x, sy = pr4.y, ezr = pr4.z, ezi = pr4.w;
                const int mask = 1 << (7 - q);
                float2 b[4];
                bool hi[4];
                if (mask == 128) {
                    b[0] = a[2]; b[1] = a[3]; b[2] = a[0]; b[3] = a[1];
                    hi[0] = false; hi[1] = false; hi[2] = true; hi[3] = true;
                } else if (mask == 64) {
                    b[0] = a[1]; b[1] = a[0]; b[2] = a[3]; b[3] = a[2];
                    hi[0] = false; hi[1] = true; hi[2] = false; hi[3] = true;
                } else {
#pragma unroll
                    for (int u = 0; u < 4; ++u) {
                        b[u].x = __shfl_xor(a[u].x, mask, 64);
                        b[u].y = __shfl_xor(a[u].y, mask, 64);
                        hi[u] = (lane & mask) != 0;
                    }
                }
#pragma unroll
                for (int u = 0; u < 4; ++u) {
                    float sgn = hi[u] ? sy : -sy;
                    float tr = cy * a[u].x + sgn * b[u].x;
                    float ti = cy * a[u].y + sgn * b[u].y;
                    float pi = hi[u] ? ezi : -ezi;
                    a[u] = make_float2(tr * ezr - ti * pi, tr * pi + ti * ezr);
                }
            }
            // fused CNOT layer: nv[i] = a[jm[i]] (one gather, depth 1)
            float2 nv[4];
#pragma unroll
            for (int u = 0; u < 4; ++u) {
                int bl = (jm[u] & 63) << 2;
                int js = jm[u] >> 6;
                float sx0 = i_as_f(__builtin_amdgcn_ds_bpermute(bl, f_as_i(a[0].x)));
                float sx1 = i_as_f(__builtin_amdgcn_ds_bpermute(bl, f_as_i(a[1].x)));
                float sx2 = i_as_f(__builtin_amdgcn_ds_bpermute(bl, f_as_i(a[2].x)));
                float sx3 = i_as_f(__builtin_amdgcn_ds_bpermute(bl, f_as_i(a[3].x)));
                float sy0 = i_as_f(__builtin_amdgcn_ds_bpermute(bl, f_as_i(a[0].y)));
                float sy1 = i_as_f(__builtin_amdgcn_ds_bpermute(bl, f_as_i(a[1].y)));
                float sy2 = i_as_f(__builtin_amdgcn_ds_bpermute(bl, f_as_i(a[2].y)));
                float sy3 = i_as_f(__builtin_amdgcn_ds_bpermute(bl, f_as_i(a[3].y)));
                nv[u].x = (js == 0) ? sx0 : (js == 1) ? sx1 : (js == 2) ? sx2 : sx3;
                nv[u].y = (js == 0) ? sy0 : (js == 1) ? sy1 : (js == 2) ? sy2 : sy3;
            }
#pragma unroll
            for (int u = 0; u < 4; ++u) a[u] = nv[u];
        }
        int pc = __popc(bid) & 3;
        float pr = (pc == 0) ? 1.f : (pc == 2) ? -1.f : 0.f;
        float pim = (pc == 1) ? -1.f : (pc == 3) ? 1.f : 0.f;
#pragma unroll
        for (int u = 0; u < 4; ++u) {
            int i = u * 64 + lane;
            g_W[i * 256 + bid] = (_Float16)(a[u].x * pr - a[u].y * pim);
            g_W[(i + 256) * 256 + bid] = (_Float16)(a[u].x * pim + a[u].y * pr);
        }
    }

    // ---------------- grid barrier (relaxed poll + acquire at exit) ---------
    __syncthreads();
    if (tid == 0) {
        __threadfence();
        int my_sense = __hip_atomic_load(&g_sense, __ATOMIC_RELAXED,
                                         __HIP_MEMORY_SCOPE_AGENT) ^ 1;
        int arrived = __hip_atomic_fetch_add(&g_ctr, 1, __ATOMIC_ACQ_REL,
                                             __HIP_MEMORY_SCOPE_AGENT) + 1;
        if (arrived == NBLK) {
            __hip_atomic_store(&g_ctr, 0, __ATOMIC_RELAXED,
                               __HIP_MEMORY_SCOPE_AGENT);
            __hip_atomic_store(&g_sense, my_sense, __ATOMIC_RELEASE,
                               __HIP_MEMORY_SCOPE_AGENT);
        } else {
            while (__hip_atomic_load(&g_sense, __ATOMIC_RELAXED,
                                     __HIP_MEMORY_SCOPE_AGENT) != my_sense) {
                __builtin_amdgcn_s_sleep(8);
            }
            (void)__hip_atomic_load(&g_sense, __ATOMIC_ACQUIRE,
                                    __HIP_MEMORY_SCOPE_AGENT);
        }
        __threadfence();
    }
    __syncthreads();

    // ---------------- B: wave wv owns i = wv*16+c (Re f=0, Im f=1) ----------
    // A/B fragment lane layouts coincide (idx = lane&15, k = g4*8+e): same regs
    // serve as the MFMA A-operand in the swapped GEMM.
    half8 bfr[2][8];
#pragma unroll
    for (int f = 0; f < 2; ++f) {
        int row = f * 256 + wv * 16 + c;
#pragma unroll
        for (int st = 0; st < 8; ++st)
            bfr[f][st] = *(const half8*)&g_W[row * 256 + st * 32 + g4 * 8];
    }

    // sign fragment (A of epilogue MFMA): row m=c -> q=c&7, k = g4*8+e = i_local,
    // zero for k>=16 (g4>=2) so garbage B there cannot contribute.
    half8 sfrag;
#pragma unroll
    for (int e = 0; e < 8; ++e) {
        int il = g4 * 8 + e;
        float sv = (g4 < 2)
            ? ((((wv * 16 + il) >> (7 - (c & 7))) & 1) ? -1.f : 1.f) : 0.f;
        sfrag[e] = (_Float16)sv;
    }

    // ---- stageB(0): A-image for samples 0..31 into A0 ----
    stage_a(smem, 0, A0_OFF, tid);
    __syncthreads();

    // ---------------- main loop: 8 groups x 32 samples, 1 barrier/group -----
    for (int g = 0; g < 8; ++g) {
        const int abase = (g & 1) ? A1_OFF : A0_OFF;
        const int pbase = (g & 1) ? P1_OFF : P0_OFF;

        // stageB(g+1) into the other A buffer (overlaps GEMM below)
        if (g < 7)
            stage_a(smem, (g + 1) * 32, (g & 1) ? A0_OFF : A1_OFF, tid);

        // ---- swapped GEMM + bpermute epilogue, per 16-sample half ----
#pragma unroll
        for (int sg = 0; sg < 2; ++sg) {
            const int sl = sg * 16 + c;
            const int rowbase = abase + sl * 512;
            const int swz = (sl & 7) << 4;
            f32x4 acc0 = (f32x4){0.f, 0.f, 0.f, 0.f};
            f32x4 acc1 = (f32x4){0.f, 0.f, 0.f, 0.f};
#pragma unroll
            for (int st = 0; st < 8; ++st) {
                half8 afr = *(const half8*)(smem + rowbase + ((st * 64 + g4 * 16) ^ swz));
                acc0 = __builtin_amdgcn_mfma_f32_16x16x32_f16(bfr[0][st], afr, acc0, 0, 0, 0);
                acc1 = __builtin_amdgcn_mfma_f32_16x16x32_f16(bfr[1][st], afr, acc1, 0, 0, 0);
            }
            // lane (c,g4), reg j: C[i_local=g4*4+j][s=c] -> p = re^2+im^2, pack fp16
            fp16x2 pk01 = __builtin_amdgcn_cvt_pkrtz(
                acc0[0] * acc0[0] + acc1[0] * acc1[0],
                acc0[1] * acc0[1] + acc1[1] * acc1[1]);
            fp16x2 pk23 = __builtin_amdgcn_cvt_pkrtz(
                acc0[2] * acc0[2] + acc1[2] * acc1[2],
                acc0[3] * acc0[3] + acc1[3] * acc1[3]);
            // B-frag for sign-MFMA: lane (c,g4) needs p[il=g4*8+e][s=c]:
            // lo (e0-3) from lane c+32*g4, hi (e4-7) from lane c+32*g4+16.
            union { fp16x2 h; int i; } u01, u23;
            u01.h = pk01; u23.h = pk23;
            int bl = (c + (g4 << 5)) << 2;
            int w0 = __builtin_amdgcn_ds_bpermute(bl, u01.i);
            int w1 = __builtin_amdgcn_ds_bpermute(bl, u23.i);
            int w2 = __builtin_amdgcn_ds_bpermute(bl + 64, u01.i);
            int w3 = __builtin_amdgcn_ds_bpermute(bl + 64, u23.i);
            bool ok = (g4 < 2);
            union { int i[4]; half8 h8; } bu;
            bu.i[0] = ok ? w0 : 0;
            bu.i[1] = ok ? w1 : 0;
            bu.i[2] = ok ? w2 : 0;
            bu.i[3] = ok ? w3 : 0;
            // D2: lane (c,g4) reg j = E[q=g4*4+j][s=c] (q<8 valid)
            f32x4 d2 = __builtin_amdgcn_mfma_f32_16x16x32_f16(
                sfrag, bu.h8, (f32x4){0.f, 0.f, 0.f, 0.f}, 0, 0, 0);
            if (ok)
                *(f32x4*)(smem + pbase + wv * 1056 + sl * 32 + g4 * 16) = d2;
        }
        __syncthreads();   // PART[g&1] ready AND A[(g+1)&1] ready

        // ---- cross-wave sum + store (overlaps next section) ----
        if (tid < 256) {
            int s2 = tid >> 3, q = tid & 7;
            const char* pb = smem + pbase + s2 * 32 + q * 4;
            float sum = 0.f;
#pragma unroll
            for (int w = 0; w < 16; ++w)
                sum += *(const float*)(pb + w * 1056);
            out[(bid * 256 + g * 32 + s2) * 8 + q] = sum;
        }
    }
}

extern "C" void kernel_launch(void* const* d_in, const int* in_sizes, int n_in,
                              void* d_out, int out_size, void* d_ws, size_t ws_size,
                              hipStream_t stream) {
    const float* x = (const float*)d_in[0];       // (65536, 8) f32
    const float* wt = (const float*)d_in[1];      // (8, 8, 2) f32
    float* out = (float*)d_out;                   // (65536, 8) f32
    (void)d_ws; (void)ws_size; (void)in_sizes; (void)n_in; (void)out_size;

    fused<<<NBLK, 1024, 0, stream>>>(x, wt, out);
}